// Round 6
// baseline (2532.035 us; speedup 1.0000x reference)
//
#include <hip/hip_runtime.h>
#include <math.h>

#define NPTS 8192
#define NPOINT 1024
#define NSAMPLE 32

typedef float v2f __attribute__((ext_vector_type(2)));

// ---------------------------------------------------------------------------
// DPP reduce step over a 64-bit key held as {hi,lo} u32 pair.
// bound_ctrl=true: invalid-source lanes read 0 = identity for u64 max.
// hi = f32 bits of bv (monotone for bv >= 0), lo = 8191-bi (max => min bi).
// ---------------------------------------------------------------------------
template <int CTRL>
__device__ __forceinline__ void dpp_kmax_step(unsigned &hi, unsigned &lo) {
  unsigned shi = (unsigned)__builtin_amdgcn_update_dpp(0, (int)hi, CTRL, 0xF, 0xF, true);
  unsigned slo = (unsigned)__builtin_amdgcn_update_dpp(0, (int)lo, CTRL, 0xF, 0xF, true);
  unsigned long long a = ((unsigned long long)hi << 32) | lo;
  unsigned long long s = ((unsigned long long)shi << 32) | slo;
  if (s > a) { hi = shi; lo = slo; }
}

// ---------------------------------------------------------------------------
// FPS v12 == v11 unchanged (two consecutive nulls on issue- and chain-cut
// theories; see fps_red2_probe below, which measures the reduce phase
// in-situ so round 7 targets the real 2230-cyc/iter breakdown).
// ---------------------------------------------------------------------------
__global__ __launch_bounds__(512, 1) void fps_kernel(const float4* __restrict__ xyz4,
                                                     float* __restrict__ new_xyz) {
#pragma clang fp contract(off)
  const int b = blockIdx.x;
  const int tid = threadIdx.x;          // 0..511
  const float4* xp4 = xyz4 + (size_t)b * NPTS;
  __shared__ float4 lpts[NPTS];                // 128 KB point copy
  __shared__ uint2 rkey[2][8];                 // per-wave {lo, hi} key
  __shared__ float4 rcand[2][8];               // per-wave winner coords
  __shared__ float4 cents[NPOINT];             // centroid staging (16 KB)
  v2f px0, py0, pz0, dd0;
  v2f px1, py1, pz1, dd1;
  v2f px2, py2, pz2, dd2;
  v2f px3, py3, pz3, dd3;
  v2f px4, py4, pz4, dd4;
  v2f px5, py5, pz5, dd5;
  v2f px6, py6, pz6, dd6;
  v2f px7, py7, pz7, dd7;
#define FPS_LOAD(J, PX, PY, PZ, PD)            \
  {                                            \
    float4 a = xp4[tid + 1024 * J];            \
    float4 c2 = xp4[tid + 1024 * J + 512];     \
    lpts[tid + 1024 * J] = a;                  \
    lpts[tid + 1024 * J + 512] = c2;           \
    PX = (v2f){a.x, c2.x};                     \
    PY = (v2f){a.y, c2.y};                     \
    PZ = (v2f){a.z, c2.z};                     \
    PD = (v2f){1e10f, 1e10f};                  \
  }
  FPS_LOAD(0, px0, py0, pz0, dd0)
  FPS_LOAD(1, px1, py1, pz1, dd1)
  FPS_LOAD(2, px2, py2, pz2, dd2)
  FPS_LOAD(3, px3, py3, pz3, dd3)
  FPS_LOAD(4, px4, py4, pz4, dd4)
  FPS_LOAD(5, px5, py5, pz5, dd5)
  FPS_LOAD(6, px6, py6, pz6, dd6)
  FPS_LOAD(7, px7, py7, pz7, dd7)
  asm volatile("" : "+v"(px0), "+v"(py0), "+v"(pz0), "+v"(px1));
  asm volatile("" : "+v"(py1), "+v"(pz1), "+v"(px2), "+v"(py2));
  asm volatile("" : "+v"(pz2), "+v"(px3), "+v"(py3), "+v"(pz3));
  asm volatile("" : "+v"(px4), "+v"(py4), "+v"(pz4), "+v"(px5));
  asm volatile("" : "+v"(py5), "+v"(pz5), "+v"(px6), "+v"(py6));
  asm volatile("" : "+v"(pz6), "+v"(px7), "+v"(py7), "+v"(pz7));
  const int wv = tid >> 6;
  const int lane = tid & 63;
  float4 c0 = xp4[0];                   // first centroid is point 0
  float cx = c0.x, cy = c0.y, cz = c0.z;
  if (tid == 0) cents[0] = make_float4(cx, cy, cz, 0.f);
  __syncthreads();                      // lpts visible before first use
  for (int s = 1; s < NPOINT; ++s) {
    const int par = s & 1;
    const v2f cxx = (v2f){cx, cx};
    const v2f cyy = (v2f){cy, cy};
    const v2f czz = (v2f){cz, cz};
    float v0, v1, v2, v3, v4, v5, v6, v7;
    int i0, i1, i2, i3, i4, i5, i6, i7;
#define FPS_DIST(J, PX, PY, PZ, PD, PV, PI)    \
  {                                            \
    v2f dx = PX - cxx;                         \
    v2f dy = PY - cyy;                         \
    v2f dz = PZ - czz;                         \
    v2f xx = dx * dx;                          \
    v2f yy = dy * dy;                          \
    v2f zz = dz * dz;                          \
    v2f d = (xx + yy) + zz;                    \
    float dmx = fminf(PD.x, d.x);              \
    float dmy = fminf(PD.y, d.y);              \
    PD.x = dmx;                                \
    PD.y = dmy;                                \
    bool c = dmy > dmx;                        \
    PV = c ? dmy : dmx;                        \
    PI = c ? (2 * J + 1) : (2 * J);            \
  }
    FPS_DIST(0, px0, py0, pz0, dd0, v0, i0)
    FPS_DIST(1, px1, py1, pz1, dd1, v1, i1)
    FPS_DIST(2, px2, py2, pz2, dd2, v2, i2)
    FPS_DIST(3, px3, py3, pz3, dd3, v3, i3)
    FPS_DIST(4, px4, py4, pz4, dd4, v4, i4)
    FPS_DIST(5, px5, py5, pz5, dd5, v5, i5)
    FPS_DIST(6, px6, py6, pz6, dd6, v6, i6)
    FPS_DIST(7, px7, py7, pz7, dd7, v7, i7)
    bool cA = v1 > v0;  float a0 = cA ? v1 : v0;  int j0 = cA ? i1 : i0;
    bool cB = v3 > v2;  float a1 = cB ? v3 : v2;  int j1 = cB ? i3 : i2;
    bool cC = v5 > v4;  float a2 = cC ? v5 : v4;  int j2 = cC ? i5 : i4;
    bool cD = v7 > v6;  float a3 = cD ? v7 : v6;  int j3 = cD ? i7 : i6;
    bool cE = a1 > a0;  float b0 = cE ? a1 : a0;  int k0 = cE ? j1 : j0;
    bool cF = a3 > a2;  float b1 = cF ? a3 : a2;  int k1 = cF ? j3 : j2;
    bool cG = b1 > b0;
    const float bv = cG ? b1 : b0;
    const int bI = cG ? k1 : k0;        // 0..15
    const int bi = tid + (bI << 9);     // global point index (n = tid+512*i)
    float4 myc = lpts[bi];              // latency hides under DPP chain
    const unsigned mhi = __float_as_uint(bv);
    const unsigned mlo = (unsigned)(8191 - bi);
    unsigned rhi = mhi, rlo = mlo;
    dpp_kmax_step<0x111>(rhi, rlo);     // row_shr:1
    dpp_kmax_step<0x112>(rhi, rlo);     // row_shr:2
    dpp_kmax_step<0x114>(rhi, rlo);     // row_shr:4
    dpp_kmax_step<0x118>(rhi, rlo);     // row_shr:8
    dpp_kmax_step<0x142>(rhi, rlo);     // row_bcast:15
    dpp_kmax_step<0x143>(rhi, rlo);     // row_bcast:31
    const unsigned Khi = (unsigned)__builtin_amdgcn_readlane((int)rhi, 63);
    const unsigned Klo = (unsigned)__builtin_amdgcn_readlane((int)rlo, 63);
    if (mhi == Khi && mlo == Klo) {
      rkey[par][wv] = make_uint2(Klo, Khi);
      rcand[par][wv] = myc;
    }
    __syncthreads();                    // the only barrier per iteration
    uint2 wk = rkey[par][lane & 7];     // ds_read_b64 (broadcast x8)
    float4 wc = rcand[par][lane & 7];   // ds_read_b128, same lgkm window
    unsigned xhi = wk.y, xlo = wk.x;
    dpp_kmax_step<0x111>(xhi, xlo);
    dpp_kmax_step<0x112>(xhi, xlo);
    dpp_kmax_step<0x114>(xhi, xlo);     // lane 7 = max over entries 0..7
    const unsigned K = (unsigned)__builtin_amdgcn_readlane((int)xlo, 7);
    const int gi = 8191 - (int)K;
    const int wstar = (gi >> 6) & 7;
    cx = __int_as_float(__builtin_amdgcn_readlane(__float_as_int(wc.x), wstar));
    cy = __int_as_float(__builtin_amdgcn_readlane(__float_as_int(wc.y), wstar));
    cz = __int_as_float(__builtin_amdgcn_readlane(__float_as_int(wc.z), wstar));
    if (tid == 0) cents[s] = make_float4(cx, cy, cz, 0.f);
  }
  __syncthreads();
  float* outp = new_xyz + (size_t)b * NPOINT * 3;
  for (int t = tid; t < 3 * NPOINT; t += 512) {
    int sI = t / 3;
    int cI = t - 3 * sI;
    const float* cf = (const float*)&cents[sI];
    outp[t] = cf[cI];
  }
}

// ---------------------------------------------------------------------------
// ABLATION PROBE (outputs go to scratch inside the xyz4 region, which setup
// rewrites every rep — zero effect on results). Identical to fps_kernel but
// the ENTIRE reduce phase (pre-barrier DPP chain -> LDS write -> barrier ->
// LDS read -> cross-wave kmax -> readlanes) is executed TWICE per iteration,
// phase 2 data-dependent on phase 1. Timing is data-independent, so:
//     t_reduce_phase = D_probe - D_fps        (per dispatch)
//     t_dist+splat   = D_fps - t_reduce_phase
// Race note: phase-2 buffers are single-banked; the phase-A barrier of
// iteration s+1 orders every wave's phase-B reads of iteration s before the
// next writes, so no hang; data races are tolerated (probe output unused).
// ---------------------------------------------------------------------------
__global__ __launch_bounds__(512, 1) void fps_red2_probe(const float4* __restrict__ xyz4,
                                                         float* __restrict__ scratch) {
#pragma clang fp contract(off)
  const int b = blockIdx.x;
  const int tid = threadIdx.x;          // 0..511
  const float4* xp4 = xyz4 + (size_t)b * NPTS;
  __shared__ float4 lpts[NPTS];                // 128 KB point copy
  __shared__ uint2 rkey[2][8];
  __shared__ float4 rcand[2][8];
  __shared__ uint2 rkey2[8];                   // phase-2 buffers
  __shared__ float4 rcand2[8];
  __shared__ float4 cents[NPOINT];
  v2f px0, py0, pz0, dd0;
  v2f px1, py1, pz1, dd1;
  v2f px2, py2, pz2, dd2;
  v2f px3, py3, pz3, dd3;
  v2f px4, py4, pz4, dd4;
  v2f px5, py5, pz5, dd5;
  v2f px6, py6, pz6, dd6;
  v2f px7, py7, pz7, dd7;
  FPS_LOAD(0, px0, py0, pz0, dd0)
  FPS_LOAD(1, px1, py1, pz1, dd1)
  FPS_LOAD(2, px2, py2, pz2, dd2)
  FPS_LOAD(3, px3, py3, pz3, dd3)
  FPS_LOAD(4, px4, py4, pz4, dd4)
  FPS_LOAD(5, px5, py5, pz5, dd5)
  FPS_LOAD(6, px6, py6, pz6, dd6)
  FPS_LOAD(7, px7, py7, pz7, dd7)
  asm volatile("" : "+v"(px0), "+v"(py0), "+v"(pz0), "+v"(px1));
  asm volatile("" : "+v"(py1), "+v"(pz1), "+v"(px2), "+v"(py2));
  asm volatile("" : "+v"(pz2), "+v"(px3), "+v"(py3), "+v"(pz3));
  asm volatile("" : "+v"(px4), "+v"(py4), "+v"(pz4), "+v"(px5));
  asm volatile("" : "+v"(py5), "+v"(pz5), "+v"(px6), "+v"(py6));
  asm volatile("" : "+v"(pz6), "+v"(px7), "+v"(py7), "+v"(pz7));
  const int wv = tid >> 6;
  const int lane = tid & 63;
  float4 c0 = xp4[0];
  float cx = c0.x, cy = c0.y, cz = c0.z;
  if (tid == 0) cents[0] = make_float4(cx, cy, cz, 0.f);
  __syncthreads();
  for (int s = 1; s < NPOINT; ++s) {
    const int par = s & 1;
    const v2f cxx = (v2f){cx, cx};
    const v2f cyy = (v2f){cy, cy};
    const v2f czz = (v2f){cz, cz};
    float v0, v1, v2, v3, v4, v5, v6, v7;
    int i0, i1, i2, i3, i4, i5, i6, i7;
    FPS_DIST(0, px0, py0, pz0, dd0, v0, i0)
    FPS_DIST(1, px1, py1, pz1, dd1, v1, i1)
    FPS_DIST(2, px2, py2, pz2, dd2, v2, i2)
    FPS_DIST(3, px3, py3, pz3, dd3, v3, i3)
    FPS_DIST(4, px4, py4, pz4, dd4, v4, i4)
    FPS_DIST(5, px5, py5, pz5, dd5, v5, i5)
    FPS_DIST(6, px6, py6, pz6, dd6, v6, i6)
    FPS_DIST(7, px7, py7, pz7, dd7, v7, i7)
    bool cA = v1 > v0;  float a0 = cA ? v1 : v0;  int j0 = cA ? i1 : i0;
    bool cB = v3 > v2;  float a1 = cB ? v3 : v2;  int j1 = cB ? i3 : i2;
    bool cC = v5 > v4;  float a2 = cC ? v5 : v4;  int j2 = cC ? i5 : i4;
    bool cD = v7 > v6;  float a3 = cD ? v7 : v6;  int j3 = cD ? i7 : i6;
    bool cE = a1 > a0;  float b0 = cE ? a1 : a0;  int k0 = cE ? j1 : j0;
    bool cF = a3 > a2;  float b1 = cF ? a3 : a2;  int k1 = cF ? j3 : j2;
    bool cG = b1 > b0;
    const float bv = cG ? b1 : b0;
    const int bI = cG ? k1 : k0;
    const int bi = tid + (bI << 9);
    float4 myc = lpts[bi];
    // ---- reduce phase, copy 1 (identical to fps_kernel) ----
    const unsigned mhi = __float_as_uint(bv);
    const unsigned mlo = (unsigned)(8191 - bi);
    unsigned rhi = mhi, rlo = mlo;
    dpp_kmax_step<0x111>(rhi, rlo);
    dpp_kmax_step<0x112>(rhi, rlo);
    dpp_kmax_step<0x114>(rhi, rlo);
    dpp_kmax_step<0x118>(rhi, rlo);
    dpp_kmax_step<0x142>(rhi, rlo);
    dpp_kmax_step<0x143>(rhi, rlo);
    const unsigned Khi = (unsigned)__builtin_amdgcn_readlane((int)rhi, 63);
    const unsigned Klo = (unsigned)__builtin_amdgcn_readlane((int)rlo, 63);
    if (mhi == Khi && mlo == Klo) {
      rkey[par][wv] = make_uint2(Klo, Khi);
      rcand[par][wv] = myc;
    }
    __syncthreads();
    uint2 wk = rkey[par][lane & 7];
    float4 wc = rcand[par][lane & 7];
    unsigned xhi = wk.y, xlo = wk.x;
    dpp_kmax_step<0x111>(xhi, xlo);
    dpp_kmax_step<0x112>(xhi, xlo);
    dpp_kmax_step<0x114>(xhi, xlo);
    const unsigned K1 = (unsigned)__builtin_amdgcn_readlane((int)xlo, 7);
    const int gi1 = 8191 - (int)K1;
    const int ws1 = (gi1 >> 6) & 7;
    float cx1 = __int_as_float(__builtin_amdgcn_readlane(__float_as_int(wc.x), ws1));
    float cy1 = __int_as_float(__builtin_amdgcn_readlane(__float_as_int(wc.y), ws1));
    float cz1 = __int_as_float(__builtin_amdgcn_readlane(__float_as_int(wc.z), ws1));
    asm volatile("" :: "v"(cy1), "v"(cz1));   // keep readlanes live
    // ---- reduce phase, copy 2 (depends on copy 1 via cx1) ----
    const unsigned mhi2 = mhi ^ (__float_as_uint(cx1) & 1u);
    const unsigned mlo2 = mlo;
    unsigned rhi2 = mhi2, rlo2 = mlo2;
    dpp_kmax_step<0x111>(rhi2, rlo2);
    dpp_kmax_step<0x112>(rhi2, rlo2);
    dpp_kmax_step<0x114>(rhi2, rlo2);
    dpp_kmax_step<0x118>(rhi2, rlo2);
    dpp_kmax_step<0x142>(rhi2, rlo2);
    dpp_kmax_step<0x143>(rhi2, rlo2);
    const unsigned Khi2 = (unsigned)__builtin_amdgcn_readlane((int)rhi2, 63);
    const unsigned Klo2 = (unsigned)__builtin_amdgcn_readlane((int)rlo2, 63);
    if (mhi2 == Khi2 && mlo2 == Klo2) {
      rkey2[wv] = make_uint2(Klo2, Khi2);
      rcand2[wv] = myc;
    }
    __syncthreads();
    uint2 wk2 = rkey2[lane & 7];
    float4 wc2 = rcand2[lane & 7];
    unsigned yhi = wk2.y, ylo = wk2.x;
    dpp_kmax_step<0x111>(yhi, ylo);
    dpp_kmax_step<0x112>(yhi, ylo);
    dpp_kmax_step<0x114>(yhi, ylo);
    const unsigned K2 = (unsigned)__builtin_amdgcn_readlane((int)ylo, 7);
    const int gi2 = 8191 - (int)K2;
    const int ws2 = (gi2 >> 6) & 7;
    cx = __int_as_float(__builtin_amdgcn_readlane(__float_as_int(wc2.x), ws2));
    cy = __int_as_float(__builtin_amdgcn_readlane(__float_as_int(wc2.y), ws2));
    cz = __int_as_float(__builtin_amdgcn_readlane(__float_as_int(wc2.z), ws2));
    if (tid == 0) cents[s] = make_float4(cx, cy, cz, 0.f);
  }
  __syncthreads();
  float* outp = scratch + (size_t)b * NPOINT * 3;
  for (int t = tid; t < 3 * NPOINT; t += 512) {
    int sI = t / 3;
    int cI = t - 3 * sI;
    const float* cf = (const float*)&cents[sI];
    outp[t] = cf[cI];
  }
}

// ---------------------------------------------------------------------------
// Ball query: one wave per center. Replicates the reference's expanded
// sq = |a|^2 + |b|^2 - 2 a.b (contract off) and first-32-by-index semantics.
// ---------------------------------------------------------------------------
__global__ __launch_bounds__(256) void bq_kernel(const float* __restrict__ xyz,
                                                 const float* __restrict__ new_xyz,
                                                 int* __restrict__ idx_out) {
#pragma clang fp contract(off)
  __shared__ int slots[4][NSAMPLE];
  const int tid = threadIdx.x;
  const int wv = tid >> 6, lane = tid & 63;
  const int gc = blockIdx.x * 4 + wv;   // global center 0..4095
  const int b = gc >> 10;
  const float* xp = xyz + (size_t)b * 3 * NPTS;
  const float* cp = new_xyz + (size_t)gc * 3;
  const float cx = cp[0], cy = cp[1], cz = cp[2];
  const float asq = (cx * cx + cy * cy) + cz * cz;
  int cnt = 0;
  for (int base = 0; base < NPTS; base += 64) {
    int n = base + lane;
    float x = xp[n], y = xp[NPTS + n], z = xp[2 * NPTS + n];
    float bsq = (x * x + y * y) + z * z;
    float ab = (x * cx + y * cy) + z * cz;
    float sq = (asq + bsq) - 2.0f * ab;
    bool inc = !(sq > 0.01f);           // same f32 threshold as reference
    unsigned long long mk = __ballot(inc);
    int pos = cnt + (int)__popcll(mk & ((1ull << lane) - 1ull));
    if (inc && pos < NSAMPLE) slots[wv][pos] = n;
    cnt += (int)__popcll(mk);
    if (cnt >= NSAMPLE) break;          // wave-uniform
  }
  __syncthreads();
  if (lane < NSAMPLE) {
    int first = slots[wv][0];           // >=1 hit guaranteed (center itself)
    int v = (lane < cnt) ? slots[wv][lane] : first;
    idx_out[(size_t)gc * NSAMPLE + lane] = v;
  }
}

// ---------------------------------------------------------------------------
// Setup (grid = 128 blocks): every block packs 256 points of the float4
// coord table xyz4[b][n] = (x,y,z,0); block 0 additionally transposes
// w3 -> w3t and folds BN (+bias) into per-channel scale/shift.
// ---------------------------------------------------------------------------
__global__ __launch_bounds__(256) void setup_kernel(
    const float* __restrict__ xyz, const float* __restrict__ w3,
    const float* __restrict__ b1, const float* __restrict__ g1, const float* __restrict__ t1,
    const float* __restrict__ m1, const float* __restrict__ v1,
    const float* __restrict__ b2, const float* __restrict__ g2, const float* __restrict__ t2,
    const float* __restrict__ m2, const float* __restrict__ v2,
    const float* __restrict__ b3, const float* __restrict__ g3, const float* __restrict__ t3,
    const float* __restrict__ m3, const float* __restrict__ v3,
    float4* __restrict__ xyz4, float* __restrict__ w3t, float* __restrict__ scsh) {
  int tid = threadIdx.x;
  int p = blockIdx.x * 256 + tid;       // 0..32767
  int bb = p >> 13, n = p & 8191;
  const float* src = xyz + (size_t)bb * 3 * NPTS;
  xyz4[p] = make_float4(src[n], src[NPTS + n], src[2 * NPTS + n], 0.f);
  if (blockIdx.x != 0) return;
  for (int i = tid; i < 8192; i += 256) {
    int o = i >> 6, c = i & 63;
    w3t[c * 128 + o] = w3[i];
  }
  if (tid < 64) {
    float s = g1[tid] / sqrtf(v1[tid] + 1e-5f);
    scsh[tid] = s;
    scsh[64 + tid] = (b1[tid] - m1[tid]) * s + t1[tid];
    float s2 = g2[tid] / sqrtf(v2[tid] + 1e-5f);
    scsh[128 + tid] = s2;
    scsh[192 + tid] = (b2[tid] - m2[tid]) * s2 + t2[tid];
  }
  if (tid < 128) {
    float s3 = g3[tid] / sqrtf(v3[tid] + 1e-5f);
    scsh[256 + tid] = s3;
    scsh[384 + tid] = (b3[tid] - m3[tid]) * s3 + t3[tid];
  }
}

// ---------------------------------------------------------------------------
// Fused gather + MLP(6->64->64->128, BN+ReLU) + max over 32 samples.
// ---------------------------------------------------------------------------
__global__ __launch_bounds__(256, 2) void mlp_kernel(
    const float* __restrict__ xyz, const float* __restrict__ points,
    const float* __restrict__ new_xyz, const int* __restrict__ idx,
    const float* __restrict__ w1, const float* __restrict__ w2,
    const float* __restrict__ w3t, const float* __restrict__ scsh,
    float* __restrict__ out) {
  __shared__ float act[256 * 64];       // exactly 64 KB -> 2 blocks/CU
  float4* act4 = (float4*)act;
  const int tid = threadIdx.x;
  const int s0 = blockIdx.x * 8;
  const int b = s0 >> 10;               // 8 | 1024 -> uniform per block
  const int g = tid >> 5;               // center within block
  const int k = tid & 31;               // sample (phase A) / channel lane (L3)
  const int gc = s0 + g;
  const float* xp = xyz + (size_t)b * 3 * NPTS;
  const float* pp = points + (size_t)b * 3 * NPTS;
  const float* cp = new_xyz + (size_t)gc * 3;
  const int n = idx[(size_t)gc * NSAMPLE + k];
  float f0 = xp[n] - cp[0];
  float f1 = xp[NPTS + n] - cp[1];
  float f2 = xp[2 * NPTS + n] - cp[2];
  float f3 = pp[n];
  float f4 = pp[NPTS + n];
  float f5 = pp[2 * NPTS + n];
  const float* sc1 = scsh;        const float* sh1 = scsh + 64;
  const float* sc2 = scsh + 128;  const float* sh2 = scsh + 192;
  const float* sc3 = scsh + 256;  const float* sh3 = scsh + 384;
  const int row = tid;

  // ---- L1: x1[o] = relu(bn(W1 @ f)) -> LDS (own row, swizzled float4) ----
#pragma unroll
  for (int oc = 0; oc < 16; ++oc) {
    float va[4];
#pragma unroll
    for (int jj = 0; jj < 4; ++jj) {
      int o = oc * 4 + jj;
      const float* wr = w1 + o * 6;     // wave-uniform -> scalar loads
      float a = f0 * wr[0] + f1 * wr[1] + f2 * wr[2] +
                f3 * wr[3] + f4 * wr[4] + f5 * wr[5];
      va[jj] = fmaxf(a * sc1[o] + sh1[o], 0.f);
    }
    act4[row * 16 + (oc ^ (row & 15))] = make_float4(va[0], va[1], va[2], va[3]);
  }

  // ---- L2: own-row contraction, 64 accumulators, uniform scalar weights ----
  float acc[64];
#pragma unroll
  for (int o = 0; o < 64; ++o) acc[o] = 0.f;
  for (int cc = 0; cc < 16; ++cc) {     // dynamic: LDS handles dynamic index
    float4 av = act4[row * 16 + (cc ^ (row & 15))];
#pragma unroll
    for (int o = 0; o < 64; ++o) {
      const float* wr = w2 + o * 64 + cc * 4;  // wave-uniform address
      acc[o] += av.x * wr[0] + av.y * wr[1] + av.z * wr[2] + av.w * wr[3];
    }
  }
  // bn+relu, overwrite own row with x2 (no cross-thread x1 readers)
#pragma unroll
  for (int oc = 0; oc < 16; ++oc) {
    float va[4];
#pragma unroll
    for (int jj = 0; jj < 4; ++jj) {
      int o = oc * 4 + jj;
      va[jj] = fmaxf(acc[o] * sc2[o] + sh2[o], 0.f);
    }
    act4[row * 16 + (oc ^ (row & 15))] = make_float4(va[0], va[1], va[2], va[3]);
  }
  __syncthreads();                      // x2 visible to whole block

  // ---- L3 + max over k: lane j owns channel o3 = p*32+j ----
  const int j = k;
  const int sb = gc & 1023;
  for (int p = 0; p < 4; ++p) {
    int o3 = p * 32 + j;
    float wreg[64];
#pragma unroll
    for (int c = 0; c < 64; ++c) wreg[c] = w3t[c * 128 + o3];  // coalesced
    float osc = sc3[o3], osh = sh3[o3];
    float vmax = 0.f;                   // post-relu values are >= 0
    for (int kk = 0; kk < 32; ++kk) {
      int r2 = g * 32 + kk;             // uniform within 32-lane group
      float a0 = 0.f, a1 = 0.f, a2 = 0.f, a3 = 0.f;
#pragma unroll
      for (int cc = 0; cc < 16; cc += 4) {
        float4 u0 = act4[r2 * 16 + ((cc + 0) ^ (r2 & 15))];  // broadcast b128
        float4 u1 = act4[r2 * 16 + ((cc + 1) ^ (r2 & 15))];
        float4 u2 = act4[r2 * 16 + ((cc + 2) ^ (r2 & 15))];
        float4 u3 = act4[r2 * 16 + ((cc + 3) ^ (r2 & 15))];
        a0 += u0.x * wreg[4*cc+0]  + u0.y * wreg[4*cc+1]  + u0.z * wreg[4*cc+2]  + u0.w * wreg[4*cc+3];
        a1 += u1.x * wreg[4*cc+4]  + u1.y * wreg[4*cc+5]  + u1.z * wreg[4*cc+6]  + u1.w * wreg[4*cc+7];
        a2 += u2.x * wreg[4*cc+8]  + u2.y * wreg[4*cc+9]  + u2.z * wreg[4*cc+10] + u2.w * wreg[4*cc+11];
        a3 += u3.x * wreg[4*cc+12] + u3.y * wreg[4*cc+13] + u3.z * wreg[4*cc+14] + u3.w * wreg[4*cc+15];
      }
      float x3 = (a0 + a1) + (a2 + a3);
      vmax = fmaxf(vmax, fmaxf(x3 * osc + osh, 0.f));
    }
    out[((size_t)b * 128 + o3) * 1024 + sb] = vmax;   // (B,128,1024)
  }
}

// ---------------------------------------------------------------------------
extern "C" void kernel_launch(void* const* d_in, const int* in_sizes, int n_in,
                              void* d_out, int out_size, void* d_ws, size_t ws_size,
                              hipStream_t stream) {
  (void)in_sizes; (void)n_in; (void)out_size; (void)ws_size;
  const float* xyz    = (const float*)d_in[0];
  const float* points = (const float*)d_in[1];
  const float* w1 = (const float*)d_in[2];
  const float* b1 = (const float*)d_in[3];
  const float* g1 = (const float*)d_in[4];
  const float* t1 = (const float*)d_in[5];
  const float* m1 = (const float*)d_in[6];
  const float* v1 = (const float*)d_in[7];
  const float* w2 = (const float*)d_in[8];
  const float* b2 = (const float*)d_in[9];
  const float* g2 = (const float*)d_in[10];
  const float* t2 = (const float*)d_in[11];
  const float* m2 = (const float*)d_in[12];
  const float* v2 = (const float*)d_in[13];
  const float* w3 = (const float*)d_in[14];
  const float* b3 = (const float*)d_in[15];
  const float* g3 = (const float*)d_in[16];
  const float* t3 = (const float*)d_in[17];
  const float* m3 = (const float*)d_in[18];
  const float* v3 = (const float*)d_in[19];

  float* wsf = (float*)d_ws;
  float* new_xyz = wsf;                         // 4*1024*3   = 12288 f
  int*   idx     = (int*)(wsf + 12288);         // 4*1024*32  = 131072 i
  float* w3t     = wsf + 12288 + 131072;        // 64*128     = 8192 f
  float* scsh    = w3t + 8192;                  // 512 f
  float4* xyz4   = (float4*)(scsh + 512);       // 4*8192 float4 = 512 KB
  float* out     = (float*)d_out;               // (4,128,1024) f32
  // probe scratch: last 64 KB INSIDE the xyz4 region (setup rewrites it
  // every rep; nothing downstream reads xyz4 after fps).
  float* probe_scratch = (float*)(xyz4 + 4 * NPTS) - 16384;

  hipLaunchKernelGGL(setup_kernel, dim3(128), dim3(256), 0, stream,
                     xyz, w3, b1, g1, t1, m1, v1, b2, g2, t2, m2, v2,
                     b3, g3, t3, m3, v3, xyz4, w3t, scsh);
  hipLaunchKernelGGL(fps_kernel, dim3(4), dim3(512), 0, stream, xyz4, new_xyz);
  hipLaunchKernelGGL(bq_kernel, dim3(1024), dim3(256), 0, stream,
                     xyz, new_xyz, idx);
  hipLaunchKernelGGL(mlp_kernel, dim3(512), dim3(256), 0, stream,
                     xyz, points, new_xyz, idx, w1, w2, w3t, scsh, out);
  // ablation probe LAST: scribbles only on probe_scratch
  hipLaunchKernelGGL(fps_red2_probe, dim3(4), dim3(512), 0, stream,
                     xyz4, probe_scratch);
}

// Round 7
// 1313.243 us; speedup vs baseline: 1.9281x; 1.9281x over previous
//
#include <hip/hip_runtime.h>
#include <math.h>

#define NPTS 8192
#define NPOINT 1024
#define NSAMPLE 32

typedef float v2f __attribute__((ext_vector_type(2)));

// ---------------------------------------------------------------------------
// Forced packed-FP32 math (VOP3P). v12 ablation: reduce phase = 810 cyc/iter,
// dist phase = 1420 cyc/iter at ~324 VALU instr/wave — ~2.5x the packed floor,
// i.e. the compiler scalarizes v2f arithmetic. These one-instruction asm
// macros guarantee v_pk_add_f32 / v_pk_mul_f32 (register-only, deps visible
// through operands, no scheduling hazard).
// ---------------------------------------------------------------------------
#define PK_ADD(D, A, B) \
  asm("v_pk_add_f32 %0, %1, %2" : "=v"(D) : "v"(A), "v"(B))
#define PK_MUL(D, A, B) \
  asm("v_pk_mul_f32 %0, %1, %2" : "=v"(D) : "v"(A), "v"(B))

// ---------------------------------------------------------------------------
// DPP reduce step over a 64-bit key held as {hi,lo} u32 pair.
// bound_ctrl=true: invalid-source lanes read 0 = identity for u64 max.
// hi = f32 bits of bv (monotone for bv >= 0), lo = 8191-bi (max => min bi).
// ---------------------------------------------------------------------------
template <int CTRL>
__device__ __forceinline__ void dpp_kmax_step(unsigned &hi, unsigned &lo) {
  unsigned shi = (unsigned)__builtin_amdgcn_update_dpp(0, (int)hi, CTRL, 0xF, 0xF, true);
  unsigned slo = (unsigned)__builtin_amdgcn_update_dpp(0, (int)lo, CTRL, 0xF, 0xF, true);
  unsigned long long a = ((unsigned long long)hi << 32) | lo;
  unsigned long long s = ((unsigned long long)shi << 32) | slo;
  if (s > a) { hi = shi; lo = slo; }
}

// ---------------------------------------------------------------------------
// FPS v13 = v11 + forced-packed dist phase. The subtraction is expressed as
// x + (-c): the centroid is negated ONCE per iteration (exact IEEE negation,
// x - c == x + (-c) bit-exactly), so no VOP3P neg modifiers are needed.
// Scalar fminf / compare / select are unchanged (no pk_min on CDNA).
// Selection semantics identical to the verified v8-v12 chain.
// ---------------------------------------------------------------------------
__global__ __launch_bounds__(512, 1) void fps_kernel(const float4* __restrict__ xyz4,
                                                     float* __restrict__ new_xyz) {
#pragma clang fp contract(off)
  const int b = blockIdx.x;
  const int tid = threadIdx.x;          // 0..511
  const float4* xp4 = xyz4 + (size_t)b * NPTS;
  __shared__ float4 lpts[NPTS];                // 128 KB point copy
  __shared__ uint2 rkey[2][8];                 // per-wave {lo, hi} key
  __shared__ float4 rcand[2][8];               // per-wave winner coords
  __shared__ float4 cents[NPOINT];             // centroid staging (16 KB)
  v2f px0, py0, pz0, dd0;
  v2f px1, py1, pz1, dd1;
  v2f px2, py2, pz2, dd2;
  v2f px3, py3, pz3, dd3;
  v2f px4, py4, pz4, dd4;
  v2f px5, py5, pz5, dd5;
  v2f px6, py6, pz6, dd6;
  v2f px7, py7, pz7, dd7;
#define FPS_LOAD(J, PX, PY, PZ, PD)            \
  {                                            \
    float4 a = xp4[tid + 1024 * J];            \
    float4 c2 = xp4[tid + 1024 * J + 512];     \
    lpts[tid + 1024 * J] = a;                  \
    lpts[tid + 1024 * J + 512] = c2;           \
    PX = (v2f){a.x, c2.x};                     \
    PY = (v2f){a.y, c2.y};                     \
    PZ = (v2f){a.z, c2.z};                     \
    PD = (v2f){1e10f, 1e10f};                  \
  }
  FPS_LOAD(0, px0, py0, pz0, dd0)
  FPS_LOAD(1, px1, py1, pz1, dd1)
  FPS_LOAD(2, px2, py2, pz2, dd2)
  FPS_LOAD(3, px3, py3, pz3, dd3)
  FPS_LOAD(4, px4, py4, pz4, dd4)
  FPS_LOAD(5, px5, py5, pz5, dd5)
  FPS_LOAD(6, px6, py6, pz6, dd6)
  FPS_LOAD(7, px7, py7, pz7, dd7)
  // Pin: defining op in asm => not rematerializable via global reload (v10).
  asm volatile("" : "+v"(px0), "+v"(py0), "+v"(pz0), "+v"(px1));
  asm volatile("" : "+v"(py1), "+v"(pz1), "+v"(px2), "+v"(py2));
  asm volatile("" : "+v"(pz2), "+v"(px3), "+v"(py3), "+v"(pz3));
  asm volatile("" : "+v"(px4), "+v"(py4), "+v"(pz4), "+v"(px5));
  asm volatile("" : "+v"(py5), "+v"(pz5), "+v"(px6), "+v"(py6));
  asm volatile("" : "+v"(pz6), "+v"(px7), "+v"(py7), "+v"(pz7));
  const int wv = tid >> 6;
  const int lane = tid & 63;
  float4 c0 = xp4[0];                   // first centroid is point 0
  float cx = c0.x, cy = c0.y, cz = c0.z;
  if (tid == 0) cents[0] = make_float4(cx, cy, cz, 0.f);
  __syncthreads();                      // lpts visible before first use
  for (int s = 1; s < NPOINT; ++s) {
    const int par = s & 1;
    // negate once (exact): x - c == x + (-c)
    const float ncx = -cx, ncy = -cy, ncz = -cz;
    const v2f ncxx = (v2f){ncx, ncx};
    const v2f ncyy = (v2f){ncy, ncy};
    const v2f nczz = (v2f){ncz, ncz};
    float v0, v1, v2, v3, v4, v5, v6, v7;
    int i0, i1, i2, i3, i4, i5, i6, i7;
#define FPS_DIST(J, PX, PY, PZ, PD, PV, PI)    \
  {                                            \
    v2f dx, dy, dz, xx, yy, zz, ss, d;         \
    PK_ADD(dx, PX, ncxx);                      \
    PK_ADD(dy, PY, ncyy);                      \
    PK_ADD(dz, PZ, nczz);                      \
    PK_MUL(xx, dx, dx);                        \
    PK_MUL(yy, dy, dy);                        \
    PK_MUL(zz, dz, dz);                        \
    PK_ADD(ss, xx, yy);                        \
    PK_ADD(d, ss, zz);                         \
    float dmx = fminf(PD.x, d.x);              \
    float dmy = fminf(PD.y, d.y);              \
    PD.x = dmx;                                \
    PD.y = dmy;                                \
    bool c = dmy > dmx;                        \
    PV = c ? dmy : dmx;                        \
    PI = c ? (2 * J + 1) : (2 * J);            \
  }
    FPS_DIST(0, px0, py0, pz0, dd0, v0, i0)
    FPS_DIST(1, px1, py1, pz1, dd1, v1, i1)
    FPS_DIST(2, px2, py2, pz2, dd2, v2, i2)
    FPS_DIST(3, px3, py3, pz3, dd3, v3, i3)
    FPS_DIST(4, px4, py4, pz4, dd4, v4, i4)
    FPS_DIST(5, px5, py5, pz5, dd5, v5, i5)
    FPS_DIST(6, px6, py6, pz6, dd6, v6, i6)
    FPS_DIST(7, px7, py7, pz7, dd7, v7, i7)
    // 3-level argmax tree; right child wins only on strict > (min index)
    bool cA = v1 > v0;  float a0 = cA ? v1 : v0;  int j0 = cA ? i1 : i0;
    bool cB = v3 > v2;  float a1 = cB ? v3 : v2;  int j1 = cB ? i3 : i2;
    bool cC = v5 > v4;  float a2 = cC ? v5 : v4;  int j2 = cC ? i5 : i4;
    bool cD = v7 > v6;  float a3 = cD ? v7 : v6;  int j3 = cD ? i7 : i6;
    bool cE = a1 > a0;  float b0 = cE ? a1 : a0;  int k0 = cE ? j1 : j0;
    bool cF = a3 > a2;  float b1 = cF ? a3 : a2;  int k1 = cF ? j3 : j2;
    bool cG = b1 > b0;
    const float bv = cG ? b1 : b0;
    const int bI = cG ? k1 : k0;        // 0..15
    const int bi = tid + (bI << 9);     // global point index (n = tid+512*i)
    float4 myc = lpts[bi];              // latency hides under DPP chain
    const unsigned mhi = __float_as_uint(bv);
    const unsigned mlo = (unsigned)(8191 - bi);
    unsigned rhi = mhi, rlo = mlo;
    dpp_kmax_step<0x111>(rhi, rlo);     // row_shr:1
    dpp_kmax_step<0x112>(rhi, rlo);     // row_shr:2
    dpp_kmax_step<0x114>(rhi, rlo);     // row_shr:4
    dpp_kmax_step<0x118>(rhi, rlo);     // row_shr:8
    dpp_kmax_step<0x142>(rhi, rlo);     // row_bcast:15
    dpp_kmax_step<0x143>(rhi, rlo);     // row_bcast:31
    const unsigned Khi = (unsigned)__builtin_amdgcn_readlane((int)rhi, 63);
    const unsigned Klo = (unsigned)__builtin_amdgcn_readlane((int)rlo, 63);
    if (mhi == Khi && mlo == Klo) {
      rkey[par][wv] = make_uint2(Klo, Khi);
      rcand[par][wv] = myc;
    }
    __syncthreads();                    // the only barrier per iteration
    uint2 wk = rkey[par][lane & 7];     // ds_read_b64 (broadcast x8)
    float4 wc = rcand[par][lane & 7];   // ds_read_b128, same lgkm window
    unsigned xhi = wk.y, xlo = wk.x;
    dpp_kmax_step<0x111>(xhi, xlo);
    dpp_kmax_step<0x112>(xhi, xlo);
    dpp_kmax_step<0x114>(xhi, xlo);     // lane 7 = max over entries 0..7
    const unsigned K = (unsigned)__builtin_amdgcn_readlane((int)xlo, 7);
    const int gi = 8191 - (int)K;
    const int wstar = (gi >> 6) & 7;
    cx = __int_as_float(__builtin_amdgcn_readlane(__float_as_int(wc.x), wstar));
    cy = __int_as_float(__builtin_amdgcn_readlane(__float_as_int(wc.y), wstar));
    cz = __int_as_float(__builtin_amdgcn_readlane(__float_as_int(wc.z), wstar));
    if (tid == 0) cents[s] = make_float4(cx, cy, cz, 0.f);
  }
  __syncthreads();
  float* outp = new_xyz + (size_t)b * NPOINT * 3;
  for (int t = tid; t < 3 * NPOINT; t += 512) {
    int sI = t / 3;
    int cI = t - 3 * sI;
    const float* cf = (const float*)&cents[sI];
    outp[t] = cf[cI];
  }
}

// ---------------------------------------------------------------------------
// Ball query: one wave per center. Replicates the reference's expanded
// sq = |a|^2 + |b|^2 - 2 a.b (contract off) and first-32-by-index semantics.
// ---------------------------------------------------------------------------
__global__ __launch_bounds__(256) void bq_kernel(const float* __restrict__ xyz,
                                                 const float* __restrict__ new_xyz,
                                                 int* __restrict__ idx_out) {
#pragma clang fp contract(off)
  __shared__ int slots[4][NSAMPLE];
  const int tid = threadIdx.x;
  const int wv = tid >> 6, lane = tid & 63;
  const int gc = blockIdx.x * 4 + wv;   // global center 0..4095
  const int b = gc >> 10;
  const float* xp = xyz + (size_t)b * 3 * NPTS;
  const float* cp = new_xyz + (size_t)gc * 3;
  const float cx = cp[0], cy = cp[1], cz = cp[2];
  const float asq = (cx * cx + cy * cy) + cz * cz;
  int cnt = 0;
  for (int base = 0; base < NPTS; base += 64) {
    int n = base + lane;
    float x = xp[n], y = xp[NPTS + n], z = xp[2 * NPTS + n];
    float bsq = (x * x + y * y) + z * z;
    float ab = (x * cx + y * cy) + z * cz;
    float sq = (asq + bsq) - 2.0f * ab;
    bool inc = !(sq > 0.01f);           // same f32 threshold as reference
    unsigned long long mk = __ballot(inc);
    int pos = cnt + (int)__popcll(mk & ((1ull << lane) - 1ull));
    if (inc && pos < NSAMPLE) slots[wv][pos] = n;
    cnt += (int)__popcll(mk);
    if (cnt >= NSAMPLE) break;          // wave-uniform
  }
  __syncthreads();
  if (lane < NSAMPLE) {
    int first = slots[wv][0];           // >=1 hit guaranteed (center itself)
    int v = (lane < cnt) ? slots[wv][lane] : first;
    idx_out[(size_t)gc * NSAMPLE + lane] = v;
  }
}

// ---------------------------------------------------------------------------
// Setup (grid = 128 blocks): every block packs 256 points of the float4
// coord table xyz4[b][n] = (x,y,z,0); block 0 additionally transposes
// w3 -> w3t and folds BN (+bias) into per-channel scale/shift.
// ---------------------------------------------------------------------------
__global__ __launch_bounds__(256) void setup_kernel(
    const float* __restrict__ xyz, const float* __restrict__ w3,
    const float* __restrict__ b1, const float* __restrict__ g1, const float* __restrict__ t1,
    const float* __restrict__ m1, const float* __restrict__ v1,
    const float* __restrict__ b2, const float* __restrict__ g2, const float* __restrict__ t2,
    const float* __restrict__ m2, const float* __restrict__ v2,
    const float* __restrict__ b3, const float* __restrict__ g3, const float* __restrict__ t3,
    const float* __restrict__ m3, const float* __restrict__ v3,
    float4* __restrict__ xyz4, float* __restrict__ w3t, float* __restrict__ scsh) {
  int tid = threadIdx.x;
  int p = blockIdx.x * 256 + tid;       // 0..32767
  int bb = p >> 13, n = p & 8191;
  const float* src = xyz + (size_t)bb * 3 * NPTS;
  xyz4[p] = make_float4(src[n], src[NPTS + n], src[2 * NPTS + n], 0.f);
  if (blockIdx.x != 0) return;
  for (int i = tid; i < 8192; i += 256) {
    int o = i >> 6, c = i & 63;
    w3t[c * 128 + o] = w3[i];
  }
  if (tid < 64) {
    float s = g1[tid] / sqrtf(v1[tid] + 1e-5f);
    scsh[tid] = s;
    scsh[64 + tid] = (b1[tid] - m1[tid]) * s + t1[tid];
    float s2 = g2[tid] / sqrtf(v2[tid] + 1e-5f);
    scsh[128 + tid] = s2;
    scsh[192 + tid] = (b2[tid] - m2[tid]) * s2 + t2[tid];
  }
  if (tid < 128) {
    float s3 = g3[tid] / sqrtf(v3[tid] + 1e-5f);
    scsh[256 + tid] = s3;
    scsh[384 + tid] = (b3[tid] - m3[tid]) * s3 + t3[tid];
  }
}

// ---------------------------------------------------------------------------
// Fused gather + MLP(6->64->64->128, BN+ReLU) + max over 32 samples.
// ---------------------------------------------------------------------------
__global__ __launch_bounds__(256, 2) void mlp_kernel(
    const float* __restrict__ xyz, const float* __restrict__ points,
    const float* __restrict__ new_xyz, const int* __restrict__ idx,
    const float* __restrict__ w1, const float* __restrict__ w2,
    const float* __restrict__ w3t, const float* __restrict__ scsh,
    float* __restrict__ out) {
  __shared__ float act[256 * 64];       // exactly 64 KB -> 2 blocks/CU
  float4* act4 = (float4*)act;
  const int tid = threadIdx.x;
  const int s0 = blockIdx.x * 8;
  const int b = s0 >> 10;               // 8 | 1024 -> uniform per block
  const int g = tid >> 5;               // center within block
  const int k = tid & 31;               // sample (phase A) / channel lane (L3)
  const int gc = s0 + g;
  const float* xp = xyz + (size_t)b * 3 * NPTS;
  const float* pp = points + (size_t)b * 3 * NPTS;
  const float* cp = new_xyz + (size_t)gc * 3;
  const int n = idx[(size_t)gc * NSAMPLE + k];
  float f0 = xp[n] - cp[0];
  float f1 = xp[NPTS + n] - cp[1];
  float f2 = xp[2 * NPTS + n] - cp[2];
  float f3 = pp[n];
  float f4 = pp[NPTS + n];
  float f5 = pp[2 * NPTS + n];
  const float* sc1 = scsh;        const float* sh1 = scsh + 64;
  const float* sc2 = scsh + 128;  const float* sh2 = scsh + 192;
  const float* sc3 = scsh + 256;  const float* sh3 = scsh + 384;
  const int row = tid;

  // ---- L1: x1[o] = relu(bn(W1 @ f)) -> LDS (own row, swizzled float4) ----
#pragma unroll
  for (int oc = 0; oc < 16; ++oc) {
    float va[4];
#pragma unroll
    for (int jj = 0; jj < 4; ++jj) {
      int o = oc * 4 + jj;
      const float* wr = w1 + o * 6;     // wave-uniform -> scalar loads
      float a = f0 * wr[0] + f1 * wr[1] + f2 * wr[2] +
                f3 * wr[3] + f4 * wr[4] + f5 * wr[5];
      va[jj] = fmaxf(a * sc1[o] + sh1[o], 0.f);
    }
    act4[row * 16 + (oc ^ (row & 15))] = make_float4(va[0], va[1], va[2], va[3]);
  }

  // ---- L2: own-row contraction, 64 accumulators, uniform scalar weights ----
  float acc[64];
#pragma unroll
  for (int o = 0; o < 64; ++o) acc[o] = 0.f;
  for (int cc = 0; cc < 16; ++cc) {     // dynamic: LDS handles dynamic index
    float4 av = act4[row * 16 + (cc ^ (row & 15))];
#pragma unroll
    for (int o = 0; o < 64; ++o) {
      const float* wr = w2 + o * 64 + cc * 4;  // wave-uniform address
      acc[o] += av.x * wr[0] + av.y * wr[1] + av.z * wr[2] + av.w * wr[3];
    }
  }
  // bn+relu, overwrite own row with x2 (no cross-thread x1 readers)
#pragma unroll
  for (int oc = 0; oc < 16; ++oc) {
    float va[4];
#pragma unroll
    for (int jj = 0; jj < 4; ++jj) {
      int o = oc * 4 + jj;
      va[jj] = fmaxf(acc[o] * sc2[o] + sh2[o], 0.f);
    }
    act4[row * 16 + (oc ^ (row & 15))] = make_float4(va[0], va[1], va[2], va[3]);
  }
  __syncthreads();                      // x2 visible to whole block

  // ---- L3 + max over k: lane j owns channel o3 = p*32+j ----
  const int j = k;
  const int sb = gc & 1023;
  for (int p = 0; p < 4; ++p) {
    int o3 = p * 32 + j;
    float wreg[64];
#pragma unroll
    for (int c = 0; c < 64; ++c) wreg[c] = w3t[c * 128 + o3];  // coalesced
    float osc = sc3[o3], osh = sh3[o3];
    float vmax = 0.f;                   // post-relu values are >= 0
    for (int kk = 0; kk < 32; ++kk) {
      int r2 = g * 32 + kk;             // uniform within 32-lane group
      float a0 = 0.f, a1 = 0.f, a2 = 0.f, a3 = 0.f;
#pragma unroll
      for (int cc = 0; cc < 16; cc += 4) {
        float4 u0 = act4[r2 * 16 + ((cc + 0) ^ (r2 & 15))];  // broadcast b128
        float4 u1 = act4[r2 * 16 + ((cc + 1) ^ (r2 & 15))];
        float4 u2 = act4[r2 * 16 + ((cc + 2) ^ (r2 & 15))];
        float4 u3 = act4[r2 * 16 + ((cc + 3) ^ (r2 & 15))];
        a0 += u0.x * wreg[4*cc+0]  + u0.y * wreg[4*cc+1]  + u0.z * wreg[4*cc+2]  + u0.w * wreg[4*cc+3];
        a1 += u1.x * wreg[4*cc+4]  + u1.y * wreg[4*cc+5]  + u1.z * wreg[4*cc+6]  + u1.w * wreg[4*cc+7];
        a2 += u2.x * wreg[4*cc+8]  + u2.y * wreg[4*cc+9]  + u2.z * wreg[4*cc+10] + u2.w * wreg[4*cc+11];
        a3 += u3.x * wreg[4*cc+12] + u3.y * wreg[4*cc+13] + u3.z * wreg[4*cc+14] + u3.w * wreg[4*cc+15];
      }
      float x3 = (a0 + a1) + (a2 + a3);
      vmax = fmaxf(vmax, fmaxf(x3 * osc + osh, 0.f));
    }
    out[((size_t)b * 128 + o3) * 1024 + sb] = vmax;   // (B,128,1024)
  }
}

// ---------------------------------------------------------------------------
extern "C" void kernel_launch(void* const* d_in, const int* in_sizes, int n_in,
                              void* d_out, int out_size, void* d_ws, size_t ws_size,
                              hipStream_t stream) {
  (void)in_sizes; (void)n_in; (void)out_size; (void)ws_size;
  const float* xyz    = (const float*)d_in[0];
  const float* points = (const float*)d_in[1];
  const float* w1 = (const float*)d_in[2];
  const float* b1 = (const float*)d_in[3];
  const float* g1 = (const float*)d_in[4];
  const float* t1 = (const float*)d_in[5];
  const float* m1 = (const float*)d_in[6];
  const float* v1 = (const float*)d_in[7];
  const float* w2 = (const float*)d_in[8];
  const float* b2 = (const float*)d_in[9];
  const float* g2 = (const float*)d_in[10];
  const float* t2 = (const float*)d_in[11];
  const float* m2 = (const float*)d_in[12];
  const float* v2 = (const float*)d_in[13];
  const float* w3 = (const float*)d_in[14];
  const float* b3 = (const float*)d_in[15];
  const float* g3 = (const float*)d_in[16];
  const float* t3 = (const float*)d_in[17];
  const float* m3 = (const float*)d_in[18];
  const float* v3 = (const float*)d_in[19];

  float* wsf = (float*)d_ws;
  float* new_xyz = wsf;                         // 4*1024*3   = 12288 f
  int*   idx     = (int*)(wsf + 12288);         // 4*1024*32  = 131072 i
  float* w3t     = wsf + 12288 + 131072;        // 64*128     = 8192 f
  float* scsh    = w3t + 8192;                  // 512 f
  float4* xyz4   = (float4*)(scsh + 512);       // 4*8192 float4 = 512 KB
  float* out     = (float*)d_out;               // (4,128,1024) f32

  hipLaunchKernelGGL(setup_kernel, dim3(128), dim3(256), 0, stream,
                     xyz, w3, b1, g1, t1, m1, v1, b2, g2, t2, m2, v2,
                     b3, g3, t3, m3, v3, xyz4, w3t, scsh);
  hipLaunchKernelGGL(fps_kernel, dim3(4), dim3(512), 0, stream, xyz4, new_xyz);
  hipLaunchKernelGGL(bq_kernel, dim3(1024), dim3(256), 0, stream,
                     xyz, new_xyz, idx);
  hipLaunchKernelGGL(mlp_kernel, dim3(512), dim3(256), 0, stream,
                     xyz, points, new_xyz, idx, w1, w2, w3t, scsh, out);
}

// Round 8
// 1217.132 us; speedup vs baseline: 2.0803x; 1.0790x over previous
//
#include <hip/hip_runtime.h>
#include <math.h>

#define NPTS 8192
#define NPOINT 1024
#define NSAMPLE 32

typedef float v2f __attribute__((ext_vector_type(2)));

// ---------------------------------------------------------------------------
// DPP reduce steps. bound_ctrl=true: invalid-source lanes read 0, which is
// the identity for both f32-max over values >=0 and u32-max.
// ---------------------------------------------------------------------------
template <int CTRL>
__device__ __forceinline__ float dpp_fmax_step(float v) {
  int s = __builtin_amdgcn_update_dpp(0, __float_as_int(v), CTRL, 0xF, 0xF, true);
  return fmaxf(v, __int_as_float(s));
}
template <int CTRL>
__device__ __forceinline__ unsigned dpp_umax_step(unsigned v) {
  int s = __builtin_amdgcn_update_dpp(0, (int)v, CTRL, 0xF, 0xF, true);
  unsigned u = (unsigned)s;
  return (u > v) ? u : v;
}

// ---------------------------------------------------------------------------
// FPS v14 == v10 exactly (the measured best: 949us fps / 1211.7us total).
// History: v11 (u64-kmax chain) = +16us; v13 (forced v_pk_* asm) = +103us.
// v12's ablation: reduce phase ~810 cyc/iter, dist+stalls ~1420 cyc/iter.
// The kernel is issue+latency mixed-bound on a 1023-step serial chain;
// remaining levers (pk_min_f32, relaxed exactness, sub-us cross-CU sync)
// don't exist on this hardware/problem. Keep the verified structure:
// register-pinned coords (v10 fix: VGPR 40->88, no L2 reloads), 128KB LDS
// point copy, two-phase DPP wave reduce, slim lane-parallel cross-wave
// reduce, lpts[gi] broadcast centroid fetch, cents LDS staging, one
// barrier/iter, zero global ops in the loop.
// Bit-exact vs numpy: contract off, ((dx*dx+dy*dy)+dz*dz), min-accumulate,
// argmax first-occurrence (strict > right-wins = min index at every level;
// cross-lane/wave ties via max(8191-bi) = min global index, keys distinct).
// ---------------------------------------------------------------------------
__global__ __launch_bounds__(512, 1) void fps_kernel(const float4* __restrict__ xyz4,
                                                     float* __restrict__ new_xyz) {
#pragma clang fp contract(off)
  const int b = blockIdx.x;
  const int tid = threadIdx.x;          // 0..511
  const float4* xp4 = xyz4 + (size_t)b * NPTS;
  __shared__ float4 lpts[NPTS];                // 128 KB point copy
  __shared__ uint2 rwk[2][8];                  // per-wave {Mw bits, K2}
  __shared__ float4 cents[NPOINT];             // centroid staging (16 KB)
  // pair J holds i=2J (.x, n=tid+1024J) and i=2J+1 (.y, n=tid+1024J+512)
  v2f px0, py0, pz0, dd0;
  v2f px1, py1, pz1, dd1;
  v2f px2, py2, pz2, dd2;
  v2f px3, py3, pz3, dd3;
  v2f px4, py4, pz4, dd4;
  v2f px5, py5, pz5, dd5;
  v2f px6, py6, pz6, dd6;
  v2f px7, py7, pz7, dd7;
#define FPS_LOAD(J, PX, PY, PZ, PD)            \
  {                                            \
    float4 a = xp4[tid + 1024 * J];            \
    float4 c2 = xp4[tid + 1024 * J + 512];     \
    lpts[tid + 1024 * J] = a;                  \
    lpts[tid + 1024 * J + 512] = c2;           \
    PX = (v2f){a.x, c2.x};                     \
    PY = (v2f){a.y, c2.y};                     \
    PZ = (v2f){a.z, c2.z};                     \
    PD = (v2f){1e10f, 1e10f};                  \
  }
  FPS_LOAD(0, px0, py0, pz0, dd0)
  FPS_LOAD(1, px1, py1, pz1, dd1)
  FPS_LOAD(2, px2, py2, pz2, dd2)
  FPS_LOAD(3, px3, py3, pz3, dd3)
  FPS_LOAD(4, px4, py4, pz4, dd4)
  FPS_LOAD(5, px5, py5, pz5, dd5)
  FPS_LOAD(6, px6, py6, pz6, dd6)
  FPS_LOAD(7, px7, py7, pz7, dd7)
  // Pin the coords: the asm becomes their defining op => the register
  // allocator cannot rematerialize them via global reloads (the v8/v9 bug).
  asm volatile("" : "+v"(px0), "+v"(py0), "+v"(pz0), "+v"(px1));
  asm volatile("" : "+v"(py1), "+v"(pz1), "+v"(px2), "+v"(py2));
  asm volatile("" : "+v"(pz2), "+v"(px3), "+v"(py3), "+v"(pz3));
  asm volatile("" : "+v"(px4), "+v"(py4), "+v"(pz4), "+v"(px5));
  asm volatile("" : "+v"(py5), "+v"(pz5), "+v"(px6), "+v"(py6));
  asm volatile("" : "+v"(pz6), "+v"(px7), "+v"(py7), "+v"(pz7));
  const int wv = tid >> 6;
  const int lane = tid & 63;
  float4 c0 = xp4[0];                   // first centroid is point 0
  float cx = c0.x, cy = c0.y, cz = c0.z;
  if (tid == 0) cents[0] = make_float4(cx, cy, cz, 0.f);
  __syncthreads();                      // lpts visible before first use
  for (int s = 1; s < NPOINT; ++s) {
    const int par = s & 1;
    const v2f cxx = (v2f){cx, cx};
    const v2f cyy = (v2f){cy, cy};
    const v2f czz = (v2f){cz, cz};
    float v0, v1, v2, v3, v4, v5, v6, v7;
    int i0, i1, i2, i3, i4, i5, i6, i7;
#define FPS_DIST(J, PX, PY, PZ, PD, PV, PI)    \
  {                                            \
    v2f dx = PX - cxx;                         \
    v2f dy = PY - cyy;                         \
    v2f dz = PZ - czz;                         \
    v2f xx = dx * dx;                          \
    v2f yy = dy * dy;                          \
    v2f zz = dz * dz;                          \
    v2f d = (xx + yy) + zz;                    \
    float dmx = fminf(PD.x, d.x);              \
    float dmy = fminf(PD.y, d.y);              \
    PD.x = dmx;                                \
    PD.y = dmy;                                \
    bool c = dmy > dmx;                        \
    PV = c ? dmy : dmx;                        \
    PI = c ? (2 * J + 1) : (2 * J);            \
  }
    FPS_DIST(0, px0, py0, pz0, dd0, v0, i0)
    FPS_DIST(1, px1, py1, pz1, dd1, v1, i1)
    FPS_DIST(2, px2, py2, pz2, dd2, v2, i2)
    FPS_DIST(3, px3, py3, pz3, dd3, v3, i3)
    FPS_DIST(4, px4, py4, pz4, dd4, v4, i4)
    FPS_DIST(5, px5, py5, pz5, dd5, v5, i5)
    FPS_DIST(6, px6, py6, pz6, dd6, v6, i6)
    FPS_DIST(7, px7, py7, pz7, dd7, v7, i7)
    // 3-level argmax tree; right child wins only on strict > (min index)
    bool cA = v1 > v0;  float a0 = cA ? v1 : v0;  int j0 = cA ? i1 : i0;
    bool cB = v3 > v2;  float a1 = cB ? v3 : v2;  int j1 = cB ? i3 : i2;
    bool cC = v5 > v4;  float a2 = cC ? v5 : v4;  int j2 = cC ? i5 : i4;
    bool cD = v7 > v6;  float a3 = cD ? v7 : v6;  int j3 = cD ? i7 : i6;
    bool cE = a1 > a0;  float b0 = cE ? a1 : a0;  int k0 = cE ? j1 : j0;
    bool cF = a3 > a2;  float b1 = cF ? a3 : a2;  int k1 = cF ? j3 : j2;
    bool cG = b1 > b0;
    const float bv = cG ? b1 : b0;
    const int bI = cG ? k1 : k0;        // 0..15
    const int bi = tid + (bI << 9);     // global point index (n = tid+512*i)
    // --- wave reduce, phase 1: max value (bv >= 0, f32 max) ---
    float m = bv;
    m = dpp_fmax_step<0x111>(m);        // row_shr:1
    m = dpp_fmax_step<0x112>(m);        // row_shr:2
    m = dpp_fmax_step<0x114>(m);        // row_shr:4
    m = dpp_fmax_step<0x118>(m);        // row_shr:8
    m = dpp_fmax_step<0x142>(m);        // row_bcast:15
    m = dpp_fmax_step<0x143>(m);        // row_bcast:31
    float Mw = __int_as_float(__builtin_amdgcn_readlane(__float_as_int(m), 63));
    // --- phase 2: among lanes at the max, min index via max(8191-bi) ---
    unsigned kc = (bv == Mw) ? (unsigned)(8191 - bi) : 0u;
    kc = dpp_umax_step<0x111>(kc);
    kc = dpp_umax_step<0x112>(kc);
    kc = dpp_umax_step<0x114>(kc);
    kc = dpp_umax_step<0x118>(kc);
    kc = dpp_umax_step<0x142>(kc);
    kc = dpp_umax_step<0x143>(kc);
    unsigned K2 = (unsigned)__builtin_amdgcn_readlane((int)kc, 63);
    // exactly one lane per wave matches (bi unique across the block)
    if (bv == Mw && (unsigned)(8191 - bi) == K2) {
      rwk[par][wv] = make_uint2(__float_as_uint(Mw), K2);
    }
    __syncthreads();                    // the only barrier per iteration
    // --- slim cross-wave reduce: lane-parallel over the 8 wave results ---
    uint2 wk = rwk[par][lane & 7];      // 8-way broadcast ds_read_b64
    float mw = __uint_as_float(wk.x);
    float mm = mw;
    mm = dpp_fmax_step<0x111>(mm);      // row_shr:1 (within row of 16)
    mm = dpp_fmax_step<0x112>(mm);      // row_shr:2
    mm = dpp_fmax_step<0x114>(mm);      // row_shr:4 -> lane 7 = max(l0..l7)
    float Mv = __int_as_float(__builtin_amdgcn_readlane(__float_as_int(mm), 7));
    unsigned kx = (mw == Mv) ? wk.y : 0u;
    kx = dpp_umax_step<0x111>(kx);
    kx = dpp_umax_step<0x112>(kx);
    kx = dpp_umax_step<0x114>(kx);
    unsigned K = (unsigned)__builtin_amdgcn_readlane((int)kx, 7);
    const int gi = 8191 - (int)K;
    float4 cc = lpts[gi];               // broadcast ds_read_b128 (uniform)
    cx = cc.x;
    cy = cc.y;
    cz = cc.z;
    if (tid == 0) cents[s] = make_float4(cx, cy, cz, 0.f);
  }
  __syncthreads();
  // coalesced one-shot dump of the 1024 centroids (12 KB)
  float* outp = new_xyz + (size_t)b * NPOINT * 3;
  for (int t = tid; t < 3 * NPOINT; t += 512) {
    int sI = t / 3;
    int cI = t - 3 * sI;
    const float* cf = (const float*)&cents[sI];
    outp[t] = cf[cI];
  }
}

// ---------------------------------------------------------------------------
// Ball query: one wave per center. Replicates the reference's expanded
// sq = |a|^2 + |b|^2 - 2 a.b (contract off) and first-32-by-index semantics.
// ---------------------------------------------------------------------------
__global__ __launch_bounds__(256) void bq_kernel(const float* __restrict__ xyz,
                                                 const float* __restrict__ new_xyz,
                                                 int* __restrict__ idx_out) {
#pragma clang fp contract(off)
  __shared__ int slots[4][NSAMPLE];
  const int tid = threadIdx.x;
  const int wv = tid >> 6, lane = tid & 63;
  const int gc = blockIdx.x * 4 + wv;   // global center 0..4095
  const int b = gc >> 10;
  const float* xp = xyz + (size_t)b * 3 * NPTS;
  const float* cp = new_xyz + (size_t)gc * 3;
  const float cx = cp[0], cy = cp[1], cz = cp[2];
  const float asq = (cx * cx + cy * cy) + cz * cz;
  int cnt = 0;
  for (int base = 0; base < NPTS; base += 64) {
    int n = base + lane;
    float x = xp[n], y = xp[NPTS + n], z = xp[2 * NPTS + n];
    float bsq = (x * x + y * y) + z * z;
    float ab = (x * cx + y * cy) + z * cz;
    float sq = (asq + bsq) - 2.0f * ab;
    bool inc = !(sq > 0.01f);           // same f32 threshold as reference
    unsigned long long mk = __ballot(inc);
    int pos = cnt + (int)__popcll(mk & ((1ull << lane) - 1ull));
    if (inc && pos < NSAMPLE) slots[wv][pos] = n;
    cnt += (int)__popcll(mk);
    if (cnt >= NSAMPLE) break;          // wave-uniform
  }
  __syncthreads();
  if (lane < NSAMPLE) {
    int first = slots[wv][0];           // >=1 hit guaranteed (center itself)
    int v = (lane < cnt) ? slots[wv][lane] : first;
    idx_out[(size_t)gc * NSAMPLE + lane] = v;
  }
}

// ---------------------------------------------------------------------------
// Setup (grid = 128 blocks): every block packs 256 points of the float4
// coord table xyz4[b][n] = (x,y,z,0); block 0 additionally transposes
// w3 -> w3t and folds BN (+bias) into per-channel scale/shift.
// ---------------------------------------------------------------------------
__global__ __launch_bounds__(256) void setup_kernel(
    const float* __restrict__ xyz, const float* __restrict__ w3,
    const float* __restrict__ b1, const float* __restrict__ g1, const float* __restrict__ t1,
    const float* __restrict__ m1, const float* __restrict__ v1,
    const float* __restrict__ b2, const float* __restrict__ g2, const float* __restrict__ t2,
    const float* __restrict__ m2, const float* __restrict__ v2,
    const float* __restrict__ b3, const float* __restrict__ g3, const float* __restrict__ t3,
    const float* __restrict__ m3, const float* __restrict__ v3,
    float4* __restrict__ xyz4, float* __restrict__ w3t, float* __restrict__ scsh) {
  int tid = threadIdx.x;
  int p = blockIdx.x * 256 + tid;       // 0..32767
  int bb = p >> 13, n = p & 8191;
  const float* src = xyz + (size_t)bb * 3 * NPTS;
  xyz4[p] = make_float4(src[n], src[NPTS + n], src[2 * NPTS + n], 0.f);
  if (blockIdx.x != 0) return;
  for (int i = tid; i < 8192; i += 256) {
    int o = i >> 6, c = i & 63;
    w3t[c * 128 + o] = w3[i];
  }
  if (tid < 64) {
    float s = g1[tid] / sqrtf(v1[tid] + 1e-5f);
    scsh[tid] = s;
    scsh[64 + tid] = (b1[tid] - m1[tid]) * s + t1[tid];
    float s2 = g2[tid] / sqrtf(v2[tid] + 1e-5f);
    scsh[128 + tid] = s2;
    scsh[192 + tid] = (b2[tid] - m2[tid]) * s2 + t2[tid];
  }
  if (tid < 128) {
    float s3 = g3[tid] / sqrtf(v3[tid] + 1e-5f);
    scsh[256 + tid] = s3;
    scsh[384 + tid] = (b3[tid] - m3[tid]) * s3 + t3[tid];
  }
}

// ---------------------------------------------------------------------------
// Fused gather + MLP(6->64->64->128, BN+ReLU) + max over 32 samples.
// Block = 256 threads = 8 centers x 32 samples. Activations live in one
// 64KB LDS buffer, XOR-swizzled at float4 granularity (conflict-free at the
// b128 bank floor). L1/L2 use (center,sample) mapping (own-row, no barrier);
// L3 uses (center,channel-lane) mapping so the k-loop folds into a register
// max (no cross-lane butterfly).
// ---------------------------------------------------------------------------
__global__ __launch_bounds__(256, 2) void mlp_kernel(
    const float* __restrict__ xyz, const float* __restrict__ points,
    const float* __restrict__ new_xyz, const int* __restrict__ idx,
    const float* __restrict__ w1, const float* __restrict__ w2,
    const float* __restrict__ w3t, const float* __restrict__ scsh,
    float* __restrict__ out) {
  __shared__ float act[256 * 64];       // exactly 64 KB -> 2 blocks/CU
  float4* act4 = (float4*)act;
  const int tid = threadIdx.x;
  const int s0 = blockIdx.x * 8;
  const int b = s0 >> 10;               // 8 | 1024 -> uniform per block
  const int g = tid >> 5;               // center within block
  const int k = tid & 31;               // sample (phase A) / channel lane (L3)
  const int gc = s0 + g;
  const float* xp = xyz + (size_t)b * 3 * NPTS;
  const float* pp = points + (size_t)b * 3 * NPTS;
  const float* cp = new_xyz + (size_t)gc * 3;
  const int n = idx[(size_t)gc * NSAMPLE + k];
  float f0 = xp[n] - cp[0];
  float f1 = xp[NPTS + n] - cp[1];
  float f2 = xp[2 * NPTS + n] - cp[2];
  float f3 = pp[n];
  float f4 = pp[NPTS + n];
  float f5 = pp[2 * NPTS + n];
  const float* sc1 = scsh;        const float* sh1 = scsh + 64;
  const float* sc2 = scsh + 128;  const float* sh2 = scsh + 192;
  const float* sc3 = scsh + 256;  const float* sh3 = scsh + 384;
  const int row = tid;

  // ---- L1: x1[o] = relu(bn(W1 @ f)) -> LDS (own row, swizzled float4) ----
#pragma unroll
  for (int oc = 0; oc < 16; ++oc) {
    float va[4];
#pragma unroll
    for (int jj = 0; jj < 4; ++jj) {
      int o = oc * 4 + jj;
      const float* wr = w1 + o * 6;     // wave-uniform -> scalar loads
      float a = f0 * wr[0] + f1 * wr[1] + f2 * wr[2] +
                f3 * wr[3] + f4 * wr[4] + f5 * wr[5];
      va[jj] = fmaxf(a * sc1[o] + sh1[o], 0.f);
    }
    act4[row * 16 + (oc ^ (row & 15))] = make_float4(va[0], va[1], va[2], va[3]);
  }

  // ---- L2: own-row contraction, 64 accumulators, uniform scalar weights ----
  float acc[64];
#pragma unroll
  for (int o = 0; o < 64; ++o) acc[o] = 0.f;
  for (int cc = 0; cc < 16; ++cc) {     // dynamic: LDS handles dynamic index
    float4 av = act4[row * 16 + (cc ^ (row & 15))];
#pragma unroll
    for (int o = 0; o < 64; ++o) {
      const float* wr = w2 + o * 64 + cc * 4;  // wave-uniform address
      acc[o] += av.x * wr[0] + av.y * wr[1] + av.z * wr[2] + av.w * wr[3];
    }
  }
  // bn+relu, overwrite own row with x2 (no cross-thread x1 readers)
#pragma unroll
  for (int oc = 0; oc < 16; ++oc) {
    float va[4];
#pragma unroll
    for (int jj = 0; jj < 4; ++jj) {
      int o = oc * 4 + jj;
      va[jj] = fmaxf(acc[o] * sc2[o] + sh2[o], 0.f);
    }
    act4[row * 16 + (oc ^ (row & 15))] = make_float4(va[0], va[1], va[2], va[3]);
  }
  __syncthreads();                      // x2 visible to whole block

  // ---- L3 + max over k: lane j owns channel o3 = p*32+j ----
  const int j = k;
  const int sb = gc & 1023;
  for (int p = 0; p < 4; ++p) {
    int o3 = p * 32 + j;
    float wreg[64];
#pragma unroll
    for (int c = 0; c < 64; ++c) wreg[c] = w3t[c * 128 + o3];  // coalesced
    float osc = sc3[o3], osh = sh3[o3];
    float vmax = 0.f;                   // post-relu values are >= 0
    for (int kk = 0; kk < 32; ++kk) {
      int r2 = g * 32 + kk;             // uniform within 32-lane group
      float a0 = 0.f, a1 = 0.f, a2 = 0.f, a3 = 0.f;
#pragma unroll
      for (int cc = 0; cc < 16; cc += 4) {
        float4 u0 = act4[r2 * 16 + ((cc + 0) ^ (r2 & 15))];  // broadcast b128
        float4 u1 = act4[r2 * 16 + ((cc + 1) ^ (r2 & 15))];
        float4 u2 = act4[r2 * 16 + ((cc + 2) ^ (r2 & 15))];
        float4 u3 = act4[r2 * 16 + ((cc + 3) ^ (r2 & 15))];
        a0 += u0.x * wreg[4*cc+0]  + u0.y * wreg[4*cc+1]  + u0.z * wreg[4*cc+2]  + u0.w * wreg[4*cc+3];
        a1 += u1.x * wreg[4*cc+4]  + u1.y * wreg[4*cc+5]  + u1.z * wreg[4*cc+6]  + u1.w * wreg[4*cc+7];
        a2 += u2.x * wreg[4*cc+8]  + u2.y * wreg[4*cc+9]  + u2.z * wreg[4*cc+10] + u2.w * wreg[4*cc+11];
        a3 += u3.x * wreg[4*cc+12] + u3.y * wreg[4*cc+13] + u3.z * wreg[4*cc+14] + u3.w * wreg[4*cc+15];
      }
      float x3 = (a0 + a1) + (a2 + a3);
      vmax = fmaxf(vmax, fmaxf(x3 * osc + osh, 0.f));
    }
    out[((size_t)b * 128 + o3) * 1024 + sb] = vmax;   // (B,128,1024)
  }
}

// ---------------------------------------------------------------------------
extern "C" void kernel_launch(void* const* d_in, const int* in_sizes, int n_in,
                              void* d_out, int out_size, void* d_ws, size_t ws_size,
                              hipStream_t stream) {
  (void)in_sizes; (void)n_in; (void)out_size; (void)ws_size;
  const float* xyz    = (const float*)d_in[0];
  const float* points = (const float*)d_in[1];
  const float* w1 = (const float*)d_in[2];
  const float* b1 = (const float*)d_in[3];
  const float* g1 = (const float*)d_in[4];
  const float* t1 = (const float*)d_in[5];
  const float* m1 = (const float*)d_in[6];
  const float* v1 = (const float*)d_in[7];
  const float* w2 = (const float*)d_in[8];
  const float* b2 = (const float*)d_in[9];
  const float* g2 = (const float*)d_in[10];
  const float* t2 = (const float*)d_in[11];
  const float* m2 = (const float*)d_in[12];
  const float* v2 = (const float*)d_in[13];
  const float* w3 = (const float*)d_in[14];
  const float* b3 = (const float*)d_in[15];
  const float* g3 = (const float*)d_in[16];
  const float* t3 = (const float*)d_in[17];
  const float* m3 = (const float*)d_in[18];
  const float* v3 = (const float*)d_in[19];

  float* wsf = (float*)d_ws;
  float* new_xyz = wsf;                         // 4*1024*3   = 12288 f
  int*   idx     = (int*)(wsf + 12288);         // 4*1024*32  = 131072 i
  float* w3t     = wsf + 12288 + 131072;        // 64*128     = 8192 f
  float* scsh    = w3t + 8192;                  // 512 f
  float4* xyz4   = (float4*)(scsh + 512);       // 4*8192 float4 = 512 KB
  float* out     = (float*)d_out;               // (4,128,1024) f32

  hipLaunchKernelGGL(setup_kernel, dim3(128), dim3(256), 0, stream,
                     xyz, w3, b1, g1, t1, m1, v1, b2, g2, t2, m2, v2,
                     b3, g3, t3, m3, v3, xyz4, w3t, scsh);
  hipLaunchKernelGGL(fps_kernel, dim3(4), dim3(512), 0, stream, xyz4, new_xyz);
  hipLaunchKernelGGL(bq_kernel, dim3(1024), dim3(256), 0, stream,
                     xyz, new_xyz, idx);
  hipLaunchKernelGGL(mlp_kernel, dim3(512), dim3(256), 0, stream,
                     xyz, points, new_xyz, idx, w1, w2, w3t, scsh, out);
}